// Round 6
// baseline (274.533 us; speedup 1.0000x reference)
//
#include <hip/hip_runtime.h>

#define DIM 256
#define KCODES 1024
#define LEVELS 4
#define CHUNK 32                 // codes per chunk
#define NCHUNK 32                // chunks per level
#define TOKB 64                  // tokens per block (2 waves x 32)
#define NTOK 65536
#define NELEM (NTOK * DIM)

typedef _Float16 h8 __attribute__((ext_vector_type(8)));
typedef _Float16 h2 __attribute__((ext_vector_type(2)));
typedef float f4 __attribute__((ext_vector_type(4)));
typedef unsigned int u32;

__device__ __forceinline__ void gload16(const void* g, void* l) {
  __builtin_amdgcn_global_load_lds(
      (const __attribute__((address_space(1))) void*)g,
      (__attribute__((address_space(3))) void*)l, 16, 0, 0);
}

// r2 accumulate over an h8 (v_dot2_f32_f16 when available: 4 instr vs 16)
__device__ __forceinline__ float sq8(h8 r, float acc) {
#if __has_builtin(__builtin_amdgcn_fdot2)
  #pragma unroll
  for (int j = 0; j < 4; ++j) {
    h2 p = {r[2 * j], r[2 * j + 1]};
    acc = __builtin_amdgcn_fdot2(p, p, acc, false);
  }
#else
  #pragma unroll
  for (int j = 0; j < 8; ++j) { float v = (float)r[j]; acc += v * v; }
#endif
  return acc;
}

// FRAGMENT-MAJOR cb16 global layout (CHUNK=32 version). Global code row
// G (0..4095), 16-B granule g (0..31, k-elements g*8..g*8+7) lives at byte
//   ((G>>5)<<14)              chunk of 32 codes, 16 KB
// + (((G>>4)&1)<<13)          nt (16-code group) within chunk, 8 KB
// + ((g>>2)<<10)              kk slot (k-block of 32 elems), 1 KB
// + (((g&3)*16 + (G&15))<<4)  lane position quad*16+col within the slot
// B-frag (nt,kk) = one contiguous 1 KB block in LANE ORDER: staging is a
// pure linear copy (fully coalesced 1 KB per gload16), and every compute
// ds_read_b128 is uniform-base + lane*16 + immediate (stride-1, conflict-
// free: verified 1.68e7 -> 2.5e4 conflict-cycles across rounds 2-4).

// Phase 0: cb fp32 -> fp16 (fragment-major, 16-B granule writes: round 4's
// 8-B scattered writes cost ~10 us); e2p = 0.25 - 0.5*||e||^2 (the +0.25
// shift keeps all MFMA scores positive so raw float bits are unsigned-order-
// monotone -> 2-op argmax tracker). Also zeroes the commit accumulator.
// Block = 256 threads = 8 half-waves; half-wave owns one code row.
__global__ __launch_bounds__(256) void rvq_prep(const float* __restrict__ cb,
                                                _Float16* __restrict__ cb16,
                                                float* __restrict__ e2p,
                                                float* __restrict__ out) {
  if (blockIdx.x == 0 && threadIdx.x == 0) out[NELEM] = 0.0f;
  const int row = blockIdx.x * 8 + (threadIdx.x >> 5);  // code row G
  const int g = threadIdx.x & 31;                       // granule
  const float* src = cb + (size_t)row * DIM + g * 8;    // coalesced 1 KB/row
  f4 a = *(const f4*)src;
  f4 b = *(const f4*)(src + 4);
  h8 hv;
  #pragma unroll
  for (int j = 0; j < 4; ++j) { hv[j] = (_Float16)a[j]; hv[4 + j] = (_Float16)b[j]; }
  char* dst = (char*)cb16 + (((size_t)row >> 5) << 14) + (((row >> 4) & 1) << 13) +
              ((g >> 2) << 10) + ((((g & 3) << 4) + (row & 15)) << 4);
  *(h8*)dst = hv;
  float s = a[0]*a[0] + a[1]*a[1] + a[2]*a[2] + a[3]*a[3] +
            b[0]*b[0] + b[1]*b[1] + b[2]*b[2] + b[3]*b[3];
  #pragma unroll
  for (int off = 16; off; off >>= 1) s += __shfl_xor(s, off, 32);
  if (g == 0) e2p[row] = 0.25f - 0.5f * s;
}

// Main fused RVQ. Round-4 compute structure (per wave: 2 m-tiles of 16,
// v_mfma_f32_16x16x32_f16, 8 independent 8-deep chains; conflict-free
// fragment-major LDS; linear coalesced staging) re-shaped for OCCUPANCY:
// TOKB=64 (2 waves/block), CHUNK=32 (16 KB chunk, 32 KB double-buffered),
// grid=1024 -> 4 blocks/CU = 16 waves/CU = 4 waves/SIMD (was 2 blocks/CU,
// 2 waves/SIMD, both pipes <50% busy = latency-bound). Per-CU MFMA/LDS/
// staging work is unchanged; four independent blocks' barrier drains and
// MFMA dependency stalls now overlap. e2 table is read straight from
// global (16 KB, L1-resident) -- e2_lds removed to fit 4 blocks in LDS.
__global__ __launch_bounds__(128, 4) void rvq_main(
    const float* __restrict__ x, const float* __restrict__ cb32,
    const _Float16* __restrict__ cb16, const float* __restrict__ e2p,
    float* __restrict__ out) {
  __shared__ __attribute__((aligned(16))) _Float16 clds[2][CHUNK * DIM];  // 32 KB
  __shared__ __attribute__((aligned(16))) int idx_hist[TOKB][4];          // 1 KB
  __shared__ float r2_sh[TOKB];
  __shared__ float csum_sh[2];

  const int tid = threadIdx.x;
  const int wave = tid >> 6, lane = tid & 63;
  const int col = lane & 15, quad = lane >> 4;

  // Staging: 16 slots/chunk (1 KB each); wave w copies slots w*8..w*8+7.
  // Linear copy: gsrc = chunk_base + slot*1024 + lane*16, ldst = slot*1024.
  const int sl_off = wave * 8192;
  const int sg0 = sl_off + (lane << 4);
  const char* cb16b = (const char*)cb16;

  // issue chunk 0 staging immediately; it flies during the x-init loads
  {
    const char* gsrc = cb16b + sg0;
    char* ldst = (char*)&clds[0][0] + sl_off;
    #pragma unroll
    for (int i = 0; i < 8; ++i) gload16(gsrc + i * 1024, ldst + i * 1024);
  }

  // ---- init: x -> fp16 A-frags + r2 partials ----
  // A-frag (16x16x32): lane holds A[row=col][k = kk*32 + quad*8 + j].
  h8 af[2][8];
  float r2p[2] = {0.f, 0.f};
  const size_t tok0 = (size_t)blockIdx.x * TOKB + wave * 32;
  #pragma unroll
  for (int mt = 0; mt < 2; ++mt) {
    const float* xr = x + (tok0 + mt * 16 + col) * DIM + quad * 8;
    #pragma unroll
    for (int kk = 0; kk < 8; ++kk) {
      f4 a = *(const f4*)(xr + kk * 32);
      f4 b = *(const f4*)(xr + kk * 32 + 4);
      h8 h;
      #pragma unroll
      for (int j = 0; j < 4; ++j) { h[j] = (_Float16)a[j]; h[4 + j] = (_Float16)b[j]; }
      af[mt][kk] = h;
      r2p[mt] = sq8(h, r2p[mt]);
    }
  }

  float commit_acc = 0.f;

  for (int lvl = 0; lvl < LEVELS; ++lvl) {
    // pre-update residual norms -> LDS (wave-local slots; commit identity)
    #pragma unroll
    for (int mt = 0; mt < 2; ++mt) {
      float s = r2p[mt];
      s += __shfl_xor(s, 16, 64);
      s += __shfl_xor(s, 32, 64);
      if (quad == 0) r2_sh[wave * 32 + mt * 16 + col] = s;
    }
    const float* e2_lvl = e2p + (lvl << 10);  // 4 KB table, L1-hot

    u32 best[2][4];
    #pragma unroll
    for (int mt = 0; mt < 2; ++mt)
      #pragma unroll
      for (int i = 0; i < 4; ++i) best[mt][i] = 0u;

    for (int c = 0; c < NCHUNK; ++c) {
      __syncthreads();  // staging of chunk c (issued a full phase ago) visible
      {
        // prefetch chunk c+1 into the other buffer (contiguous across levels;
        // clamp keeps the last iteration in-bounds, write is harmless)
        const int gn = lvl * NCHUNK + c + 1;
        const char* gsrc = cb16b + ((size_t)(gn < 128 ? gn : 127) << 14) + sg0;
        char* ldst = (char*)&clds[(c + 1) & 1][0] + sl_off;
        #pragma unroll
        for (int i = 0; i < 8; ++i) gload16(gsrc + i * 1024, ldst + i * 1024);
      }

      const char* cbuf = (const char*)&clds[c & 1][0] + (lane << 4);
      #pragma unroll
      for (int nt = 0; nt < 2; ++nt) {
        const int code0 = c * 32 + nt * 16;
        const float e2v = e2_lvl[code0 + col];  // 0.25 - ||e||^2/2
        f4 acc0 = {e2v, e2v, e2v, e2v};
        f4 acc1 = acc0;
        #pragma unroll
        for (int kk = 0; kk < 8; ++kk) {
          h8 b = *(const h8*)(cbuf + ((nt * 8 + kk) << 10));  // imm offset, stride-1
          acc0 = __builtin_amdgcn_mfma_f32_16x16x32_f16(af[0][kk], b, acc0, 0, 0, 0);
          acc1 = __builtin_amdgcn_mfma_f32_16x16x32_f16(af[1][kk], b, acc1, 0, 0, 0);
        }
        // scores all positive -> raw bits unsigned-monotone; pack
        // (bits & ~1023) | (1023-code): umax == argmax, smaller-index ties
        const u32 invc = (u32)(code0 + col) ^ 1023u;
        #pragma unroll
        for (int i = 0; i < 4; ++i) {
          u32 p0 = (__float_as_uint(acc0[i]) & 0xFFFFFC00u) | invc;
          if (p0 > best[0][i]) best[0][i] = p0;
          u32 p1 = (__float_as_uint(acc1[i]) & 0xFFFFFC00u) | invc;
          if (p1 > best[1][i]) best[1][i] = p1;
        }
      }
    }

    // reduce best across the 16 column lanes
    #pragma unroll
    for (int mt = 0; mt < 2; ++mt)
      #pragma unroll
      for (int i = 0; i < 4; ++i) {
        u32 b = best[mt][i];
        #pragma unroll
        for (int off = 1; off < 16; off <<= 1) {
          u32 o = __shfl_xor(b, off, 16);
          if (o > b) b = o;
        }
        best[mt][i] = b;
      }

    if (col == 0) {
      // C/D layout 16x16: col=lane&15, row=quad*4+i
      #pragma unroll
      for (int mt = 0; mt < 2; ++mt)
        #pragma unroll
        for (int i = 0; i < 4; ++i) {
          const u32 p = best[mt][i];
          const int code = (int)((p & 1023u) ^ 1023u);
          const int t = wave * 32 + mt * 16 + quad * 4 + i;
          idx_hist[t][lvl] = code;
          const float sc = __uint_as_float(p & 0xFFFFFC00u) - 0.25f;  // r.e - e^2/2
          commit_acc += r2_sh[t] - 2.0f * sc;  // dist = ||r||^2 - 2*sc
        }
    }
    __syncthreads();  // idx_hist visible to all waves

    if (lvl < LEVELS - 1) {  // fp16 residual update + next-level r2
      r2p[0] = 0.f; r2p[1] = 0.f;
      #pragma unroll
      for (int mt = 0; mt < 2; ++mt) {
        const int qidx = idx_hist[wave * 32 + mt * 16 + col][lvl];
        // fragment-major address of code row G, this thread's quad granules
        const int G = (lvl << 10) + qidx;
        const char* qbase = cb16b + ((size_t)(G >> 5) << 14) + (((G >> 4) & 1) << 13) +
                            ((quad * 16 + (G & 15)) << 4);
        #pragma unroll
        for (int kk = 0; kk < 8; ++kk) {
          h8 q = *(const h8*)(qbase + (kk << 10));
          h8 r = af[mt][kk] - q;
          af[mt][kk] = r;
          r2p[mt] = sq8(r, r2p[mt]);
        }
      }
    }
  }

  // ---- epilogue: y = sum_l q_l, fp32-exact, fully coalesced ----
  float* yblk = out + (size_t)blockIdx.x * (TOKB * DIM);
  #pragma unroll 4
  for (int it = 0; it < 32; ++it) {
    const int f = it * 512 + tid * 4;
    const int t = f >> 8;  // wave-uniform token
    const int d = f & 255;
    const int4 qi = *(const int4*)&idx_hist[t][0];
    f4 q0 = *(const f4*)(cb32 + (size_t)qi.x * DIM + d);
    f4 q1 = *(const f4*)(cb32 + (size_t)(1024 + qi.y) * DIM + d);
    f4 q2 = *(const f4*)(cb32 + (size_t)(2048 + qi.z) * DIM + d);
    f4 q3 = *(const f4*)(cb32 + (size_t)(3072 + qi.w) * DIM + d);
    f4 yv = (q0 + q1) + (q2 + q3);
    *(f4*)(yblk + f) = yv;
  }

  // ---- commit: butterfly + one atomic per block ----
  #pragma unroll
  for (int off = 1; off < 64; off <<= 1) commit_acc += __shfl_xor(commit_acc, off, 64);
  if (lane == 0) csum_sh[wave] = commit_acc;
  __syncthreads();
  if (tid == 0) {
    atomicAdd(out + NELEM, (csum_sh[0] + csum_sh[1]) * (0.25f / 16777216.0f));  // BETA/(N*D)
  }
}

extern "C" void kernel_launch(void* const* d_in, const int* in_sizes, int n_in,
                              void* d_out, int out_size, void* d_ws, size_t ws_size,
                              hipStream_t stream) {
  const float* x = (const float*)d_in[0];
  const float* cb = (const float*)d_in[1];
  float* out = (float*)d_out;
  _Float16* cb16 = (_Float16*)d_ws;  // 2 MiB, fragment-major
  float* e2p = (float*)((char*)d_ws + (size_t)LEVELS * KCODES * DIM * sizeof(_Float16));

  rvq_prep<<<(LEVELS * KCODES) / 8, 256, 0, stream>>>(cb, cb16, e2p, out);
  rvq_main<<<NTOK / TOKB, 128, 0, stream>>>(x, cb, cb16, e2p, out);
}

// Round 7
// 258.756 us; speedup vs baseline: 1.0610x; 1.0610x over previous
//
#include <hip/hip_runtime.h>

#define DIM 256
#define KCODES 1024
#define LEVELS 4
#define CHUNK 64                 // codes per chunk
#define NCHUNK 16
#define TOKB 128                 // tokens per block (4 waves x 32)
#define NTOK 65536
#define NELEM (NTOK * DIM)

typedef _Float16 h8 __attribute__((ext_vector_type(8)));
typedef _Float16 h2 __attribute__((ext_vector_type(2)));
typedef float f4 __attribute__((ext_vector_type(4)));
typedef unsigned int u32;

__device__ __forceinline__ void gload16(const void* g, void* l) {
  __builtin_amdgcn_global_load_lds(
      (const __attribute__((address_space(1))) void*)g,
      (__attribute__((address_space(3))) void*)l, 16, 0, 0);
}

// r2 accumulate over an h8 (v_dot2_f32_f16 when available: 4 instr vs 16)
__device__ __forceinline__ float sq8(h8 r, float acc) {
#if __has_builtin(__builtin_amdgcn_fdot2)
  #pragma unroll
  for (int j = 0; j < 4; ++j) {
    h2 p = {r[2 * j], r[2 * j + 1]};
    acc = __builtin_amdgcn_fdot2(p, p, acc, false);
  }
#else
  #pragma unroll
  for (int j = 0; j < 8; ++j) { float v = (float)r[j]; acc += v * v; }
#endif
  return acc;
}

// FRAGMENT-MAJOR cb16 global layout (CHUNK=64). Global code row G (0..4095),
// 16-B granule g (0..31, k-elements g*8..g*8+7) lives at byte
//   ((G>>6)<<15)              chunk of 64 codes, 32 KB
// + (((G>>4)&3)<<13)          nt (16-code group) within chunk, 8 KB
// + ((g>>2)<<10)              kk slot (k-block of 32 elems), 1 KB
// + (((g&3)*16 + (G&15))<<4)  lane position quad*16+col within the slot
// B-frag (nt,kk) = one contiguous 1 KB block in LANE ORDER: staging is a
// pure linear copy (fully coalesced 1 KB per gload16), and every compute
// ds_read_b128 is uniform-base + lane*16 + immediate (stride-1, conflict-
// free: verified 1.68e7 -> 2.5e4 conflict-cycles across rounds 2-4).

// Phase 0: cb fp32 -> fp16 (fragment-major, 16-B h8 writes: round-4's 8-B
// scattered writes cost ~10 us, fixed per round 6); e2p = 0.25 - 0.5*||e||^2
// (the +0.25 shift keeps all MFMA scores positive so raw float bits are
// unsigned-order-monotone -> 2-op argmax tracker). Also zeroes the commit
// accumulator (out is re-poisoned by the harness before every call).
// Block = 256 threads = 8 half-waves; half-wave owns one code row.
__global__ __launch_bounds__(256) void rvq_prep(const float* __restrict__ cb,
                                                _Float16* __restrict__ cb16,
                                                float* __restrict__ e2p,
                                                float* __restrict__ out) {
  if (blockIdx.x == 0 && threadIdx.x == 0) out[NELEM] = 0.0f;
  const int row = blockIdx.x * 8 + (threadIdx.x >> 5);  // code row G
  const int g = threadIdx.x & 31;                       // granule
  const float* src = cb + (size_t)row * DIM + g * 8;    // coalesced 1 KB/row
  f4 a = *(const f4*)src;
  f4 b = *(const f4*)(src + 4);
  h8 hv;
  #pragma unroll
  for (int j = 0; j < 4; ++j) { hv[j] = (_Float16)a[j]; hv[4 + j] = (_Float16)b[j]; }
  char* dst = (char*)cb16 + (((size_t)row >> 6) << 15) + (((row >> 4) & 3) << 13) +
              ((g >> 2) << 10) + ((((g & 3) << 4) + (row & 15)) << 4);
  *(h8*)dst = hv;
  float s = a[0]*a[0] + a[1]*a[1] + a[2]*a[2] + a[3]*a[3] +
            b[0]*b[0] + b[1]*b[1] + b[2]*b[2] + b[3]*b[3];
  #pragma unroll
  for (int off = 16; off; off >>= 1) s += __shfl_xor(s, off, 32);
  if (g == 0) e2p[row] = 0.25f - 0.5f * s;
}

// Main fused RVQ — round-4 structure (best measured: 172.6 us steady).
// 4 waves x 32 tokens (2 m-tiles of 16, v_mfma_f32_16x16x32_f16, 8
// independent 8-deep chains/wave), conflict-free fragment-major LDS,
// linear coalesced staging, chunks double-buffered with one barrier per
// chunk (prefetch issued right after the barrier drains a full compute
// phase later). Waves are structurally capped at 8/CU (2048 waves total);
// phase count capped at 64 by the LDS budget (round-6 measurement:
// ~0.48 us fixed overhead per barrier-phase). NEW this round: T5
// s_setprio(1) around each nt's ds_read+MFMA cluster — the CU hosts 2
// independent blocks whose phases drift, so MFMA-cluster waves can be
// favored over staging/packing waves (phase-diversity prerequisite holds,
// unlike lockstep m190).
__global__ __launch_bounds__(256, 2) void rvq_main(
    const float* __restrict__ x, const float* __restrict__ cb32,
    const _Float16* __restrict__ cb16, const float* __restrict__ e2p,
    float* __restrict__ out) {
  __shared__ __attribute__((aligned(16))) _Float16 clds[2][CHUNK * DIM];  // 64 KB
  __shared__ __attribute__((aligned(16))) float e2_lds[KCODES];           // 4 KB
  __shared__ __attribute__((aligned(16))) int idx_hist[TOKB][4];          // 2 KB
  __shared__ float r2_sh[TOKB];
  __shared__ float csum_sh[4];

  const int tid = threadIdx.x;
  const int wave = tid >> 6, lane = tid & 63;
  const int col = lane & 15, quad = lane >> 4;

  // Staging: 32 slots/chunk (1 KB each); wave w copies slots w*8..w*8+7.
  // Linear copy: gsrc = chunk_base + slot*1024 + lane*16, ldst = slot*1024.
  const int sl_off = wave * 8192;
  const int sg0 = sl_off + (lane << 4);
  const char* cb16b = (const char*)cb16;

  // issue chunk 0 staging immediately; it flies during the x-init loads
  {
    const char* gsrc = cb16b + sg0;
    char* ldst = (char*)&clds[0][0] + sl_off;
    #pragma unroll
    for (int i = 0; i < 8; ++i) gload16(gsrc + i * 1024, ldst + i * 1024);
  }

  // ---- init: x -> fp16 A-frags + r2 partials ----
  // A-frag (16x16x32): lane holds A[row=col][k = kk*32 + quad*8 + j].
  h8 af[2][8];
  float r2p[2] = {0.f, 0.f};
  const size_t tok0 = (size_t)blockIdx.x * TOKB + wave * 32;
  #pragma unroll
  for (int mt = 0; mt < 2; ++mt) {
    const float* xr = x + (tok0 + mt * 16 + col) * DIM + quad * 8;
    #pragma unroll
    for (int kk = 0; kk < 8; ++kk) {
      f4 a = *(const f4*)(xr + kk * 32);
      f4 b = *(const f4*)(xr + kk * 32 + 4);
      h8 h;
      #pragma unroll
      for (int j = 0; j < 4; ++j) { h[j] = (_Float16)a[j]; h[4 + j] = (_Float16)b[j]; }
      af[mt][kk] = h;
      r2p[mt] = sq8(h, r2p[mt]);
    }
  }

  float commit_acc = 0.f;

  for (int lvl = 0; lvl < LEVELS; ++lvl) {
    // pre-update residual norms -> LDS (wave-local slots; commit identity)
    #pragma unroll
    for (int mt = 0; mt < 2; ++mt) {
      float s = r2p[mt];
      s += __shfl_xor(s, 16, 64);
      s += __shfl_xor(s, 32, 64);
      if (quad == 0) r2_sh[wave * 32 + mt * 16 + col] = s;
    }
    // this level's shifted-e2 table (prev level's readers done: post-idx barrier)
    *(f4*)&e2_lds[tid * 4] = *(const f4*)(e2p + (lvl << 10) + tid * 4);

    u32 best[2][4];
    #pragma unroll
    for (int mt = 0; mt < 2; ++mt)
      #pragma unroll
      for (int i = 0; i < 4; ++i) best[mt][i] = 0u;

    for (int c = 0; c < NCHUNK; ++c) {
      __syncthreads();  // staging of chunk c (issued a full phase ago) visible
      {
        // prefetch chunk c+1 into the other buffer (contiguous across levels;
        // clamp keeps the last iteration in-bounds, write is harmless)
        const int gn = lvl * NCHUNK + c + 1;
        const char* gsrc = cb16b + ((size_t)(gn < 64 ? gn : 63) << 15) + sg0;
        char* ldst = (char*)&clds[(c + 1) & 1][0] + sl_off;
        #pragma unroll
        for (int i = 0; i < 8; ++i) gload16(gsrc + i * 1024, ldst + i * 1024);
      }

      const char* cbuf = (const char*)&clds[c & 1][0] + (lane << 4);
      #pragma unroll
      for (int nt = 0; nt < 4; ++nt) {
        const int code0 = c * 64 + nt * 16;
        const float e2v = e2_lds[code0 + col];  // 0.25 - ||e||^2/2
        f4 acc0 = {e2v, e2v, e2v, e2v};
        f4 acc1 = acc0;
        __builtin_amdgcn_s_setprio(1);  // favor MFMA-cluster waves (T5)
        #pragma unroll
        for (int kk = 0; kk < 8; ++kk) {
          h8 b = *(const h8*)(cbuf + ((nt * 8 + kk) << 10));  // imm offset, stride-1
          acc0 = __builtin_amdgcn_mfma_f32_16x16x32_f16(af[0][kk], b, acc0, 0, 0, 0);
          acc1 = __builtin_amdgcn_mfma_f32_16x16x32_f16(af[1][kk], b, acc1, 0, 0, 0);
        }
        __builtin_amdgcn_s_setprio(0);
        // scores all positive -> raw bits unsigned-monotone; pack
        // (bits & ~1023) | (1023-code): umax == argmax, smaller-index ties
        const u32 invc = (u32)(code0 + col) ^ 1023u;
        #pragma unroll
        for (int i = 0; i < 4; ++i) {
          u32 p0 = (__float_as_uint(acc0[i]) & 0xFFFFFC00u) | invc;
          if (p0 > best[0][i]) best[0][i] = p0;
          u32 p1 = (__float_as_uint(acc1[i]) & 0xFFFFFC00u) | invc;
          if (p1 > best[1][i]) best[1][i] = p1;
        }
      }
    }

    // reduce best across the 16 column lanes
    #pragma unroll
    for (int mt = 0; mt < 2; ++mt)
      #pragma unroll
      for (int i = 0; i < 4; ++i) {
        u32 b = best[mt][i];
        #pragma unroll
        for (int off = 1; off < 16; off <<= 1) {
          u32 o = __shfl_xor(b, off, 16);
          if (o > b) b = o;
        }
        best[mt][i] = b;
      }

    if (col == 0) {
      // C/D layout 16x16: col=lane&15, row=quad*4+i
      #pragma unroll
      for (int mt = 0; mt < 2; ++mt)
        #pragma unroll
        for (int i = 0; i < 4; ++i) {
          const u32 p = best[mt][i];
          const int code = (int)((p & 1023u) ^ 1023u);
          const int t = wave * 32 + mt * 16 + quad * 4 + i;
          idx_hist[t][lvl] = code;
          const float sc = __uint_as_float(p & 0xFFFFFC00u) - 0.25f;  // r.e - e^2/2
          commit_acc += r2_sh[t] - 2.0f * sc;  // dist = ||r||^2 - 2*sc
        }
    }
    __syncthreads();  // idx_hist visible to all; e2_lds free for next level

    if (lvl < LEVELS - 1) {  // fp16 residual update + next-level r2
      r2p[0] = 0.f; r2p[1] = 0.f;
      #pragma unroll
      for (int mt = 0; mt < 2; ++mt) {
        const int qidx = idx_hist[wave * 32 + mt * 16 + col][lvl];
        // fragment-major address of code row G, this thread's quad granules
        const int G = (lvl << 10) + qidx;
        const char* qbase = cb16b + ((size_t)(G >> 6) << 15) + (((G >> 4) & 3) << 13) +
                            ((quad * 16 + (G & 15)) << 4);
        #pragma unroll
        for (int kk = 0; kk < 8; ++kk) {
          h8 q = *(const h8*)(qbase + (kk << 10));
          h8 r = af[mt][kk] - q;
          af[mt][kk] = r;
          r2p[mt] = sq8(r, r2p[mt]);
        }
      }
    }
  }

  // ---- epilogue: y = sum_l q_l, fp32-exact, fully coalesced ----
  float* yblk = out + (size_t)blockIdx.x * (TOKB * DIM);
  #pragma unroll 4
  for (int it = 0; it < 32; ++it) {
    const int f = it * 1024 + tid * 4;
    const int t = f >> 8;  // wave-uniform token
    const int d = f & 255;
    const int4 qi = *(const int4*)&idx_hist[t][0];
    f4 q0 = *(const f4*)(cb32 + (size_t)qi.x * DIM + d);
    f4 q1 = *(const f4*)(cb32 + (size_t)(1024 + qi.y) * DIM + d);
    f4 q2 = *(const f4*)(cb32 + (size_t)(2048 + qi.z) * DIM + d);
    f4 q3 = *(const f4*)(cb32 + (size_t)(3072 + qi.w) * DIM + d);
    f4 yv = (q0 + q1) + (q2 + q3);
    *(f4*)(yblk + f) = yv;
  }

  // ---- commit: butterfly + one atomic per block ----
  #pragma unroll
  for (int off = 1; off < 64; off <<= 1) commit_acc += __shfl_xor(commit_acc, off, 64);
  if (lane == 0) csum_sh[wave] = commit_acc;
  __syncthreads();
  if (tid == 0) {
    const float tot = csum_sh[0] + csum_sh[1] + csum_sh[2] + csum_sh[3];
    atomicAdd(out + NELEM, tot * (0.25f / 16777216.0f));  // BETA / (N*D)
  }
}

extern "C" void kernel_launch(void* const* d_in, const int* in_sizes, int n_in,
                              void* d_out, int out_size, void* d_ws, size_t ws_size,
                              hipStream_t stream) {
  const float* x = (const float*)d_in[0];
  const float* cb = (const float*)d_in[1];
  float* out = (float*)d_out;
  _Float16* cb16 = (_Float16*)d_ws;  // 2 MiB, fragment-major
  float* e2p = (float*)((char*)d_ws + (size_t)LEVELS * KCODES * DIM * sizeof(_Float16));

  rvq_prep<<<(LEVELS * KCODES) / 8, 256, 0, stream>>>(cb, cb16, e2p, out);
  rvq_main<<<NTOK / TOKB, 256, 0, stream>>>(x, cb, cb16, e2p, out);
}